// Round 6
// baseline (232.175 us; speedup 1.0000x reference)
//
#include <hip/hip_runtime.h>

#define N_DRUG 572
#define DIM 512
#define MAXDEG 32
#define FS 3             // scan LDS stride: 2 cols + 1 pad

// ---------------------------------------------------------------------------
// prep_kernel: one launch, two independent jobs split by block range.
//  blocks [0,512):  pack linW (1024x512) into K-major panels
//                   linP[c>>6][k4][c&63][4k] -> gemm_h reads 1KB dwordx4/4k.
//  blocks [512,928): relaP[200][512] = relaW @ Wa^T.  score = drugE . relaP[rel]
// ---------------------------------------------------------------------------
__global__ __launch_bounds__(256) void prep_kernel(
    const float* __restrict__ Wa, const float* __restrict__ relaW,
    const float* __restrict__ linW, float* __restrict__ linP,
    float* __restrict__ relaP)
{
    const int b = blockIdx.x;
    const int t = threadIdx.x;
    if (b < 512) {                          // ---- pack linW ----
        const int g = b * 256 + t;          // [0,131072)
        const int c = g & 511, k4 = g >> 9; // k4 in [0,256)
        const float4 v = make_float4(linW[(size_t)(k4 * 4 + 0) * 512 + c],
                                     linW[(size_t)(k4 * 4 + 1) * 512 + c],
                                     linW[(size_t)(k4 * 4 + 2) * 512 + c],
                                     linW[(size_t)(k4 * 4 + 3) * 512 + c]);
        *(float4*)&linP[((size_t)(c >> 6) * 256 + k4) * 256 + (c & 63) * 4] = v;
        return;
    }
    // ---- relaP = relaW @ Wa^T ----
    const int bb = b - 512;                 // [0,416): 13 r-groups x 32 k-panels
    const int rb = bb >> 5, kb = bb & 31;
    const int wv = t >> 6, l = t & 63;
    const int r0 = rb * 16 + wv * 4;        // 4 rows per wave
    const int k0 = kb * 16;                 // 16 output cols per wave

    float a[4][8];
    #pragma unroll
    for (int rr = 0; rr < 4; ++rr) {
        const float4* ap = (const float4*)(relaW + (size_t)min(r0 + rr, 199) * 512 + l * 8);
        const float4 x = ap[0], y = ap[1];
        a[rr][0] = x.x; a[rr][1] = x.y; a[rr][2] = x.z; a[rr][3] = x.w;
        a[rr][4] = y.x; a[rr][5] = y.y; a[rr][6] = y.z; a[rr][7] = y.w;
    }
    float acc[64];
    #pragma unroll
    for (int i = 0; i < 64; ++i) acc[i] = 0.f;
    #pragma unroll
    for (int kk = 0; kk < 16; ++kk) {       // full unroll: acc index compile-time
        const float4* bp = (const float4*)(Wa + (size_t)(k0 + kk) * 512 + l * 8);
        const float4 x = bp[0], y = bp[1];
        const float bv[8] = {x.x, x.y, x.z, x.w, y.x, y.y, y.z, y.w};
        #pragma unroll
        for (int rr = 0; rr < 4; ++rr) {
            float s = acc[rr * 16 + kk];
            #pragma unroll
            for (int j = 0; j < 8; ++j) s = fmaf(a[rr][j], bv[j], s);
            acc[rr * 16 + kk] = s;
        }
    }
    #pragma unroll
    for (int off = 1; off <= 32; off <<= 1) {
        #pragma unroll
        for (int i = 0; i < 64; ++i) acc[i] += __shfl_xor(acc[i], off, 64);
    }
    float outv = acc[0];
    #pragma unroll
    for (int i = 1; i < 64; ++i) outv = (l == i) ? acc[i] : outv;
    const int rr = l >> 4, kk = l & 15;
    if (r0 + rr < 200) relaP[(size_t)(r0 + rr) * 512 + k0 + kk] = outv;
}

// ---------------------------------------------------------------------------
// attn_kernel: one block per drug. scores (vs relaP) -> softmax -> agg gather.
// Writes cat[d] = [agg | drug_e]. (unchanged)
// ---------------------------------------------------------------------------
__global__ __launch_bounds__(256) void attn_kernel(
    const float* __restrict__ drugW, const float* __restrict__ relaP,
    const float* __restrict__ entW, const int* __restrict__ dn,
    const int* __restrict__ adj_tail, const int* __restrict__ adj_rel,
    float* __restrict__ cat)
{
    __shared__ float at[64];
    __shared__ int tails[64];
    __shared__ int rels[64];
    const int d = blockIdx.x;
    const int t = threadIdx.x;
    const int w = t >> 6, lane = t & 63;

    if (t < 64) {
        tails[t] = adj_tail[d * 64 + t];
        rels[t]  = adj_rel[d * 64 + t];
    }
    const int rd = dn[d];
    float qv[8];
    {
        const float4* qp = (const float4*)(drugW + (size_t)rd * 512 + lane * 8);
        const float4 x = qp[0], y = qp[1];
        qv[0] = x.x; qv[1] = x.y; qv[2] = x.z; qv[3] = x.w;
        qv[4] = y.x; qv[5] = y.y; qv[6] = y.z; qv[7] = y.w;
    }
    __syncthreads();

    #pragma unroll 4
    for (int kk = 0; kk < 16; ++kk) {
        const int k = w * 16 + kk;
        const float4* p = (const float4*)(relaP + (size_t)rels[k] * 512 + lane * 8);
        const float4 x = p[0], y = p[1];
        float s = 0.f;
        s = fmaf(qv[0], x.x, s); s = fmaf(qv[1], x.y, s);
        s = fmaf(qv[2], x.z, s); s = fmaf(qv[3], x.w, s);
        s = fmaf(qv[4], y.x, s); s = fmaf(qv[5], y.y, s);
        s = fmaf(qv[6], y.z, s); s = fmaf(qv[7], y.w, s);
        #pragma unroll
        for (int off = 32; off >= 1; off >>= 1) s += __shfl_xor(s, off, 64);
        if (lane == 0) at[k] = s * 0.0441941738241592f;   // 1/sqrt(512)
    }
    __syncthreads();

    if (w == 0) {
        const float s = at[lane];
        float m = s;
        #pragma unroll
        for (int off = 32; off >= 1; off >>= 1) m = fmaxf(m, __shfl_xor(m, off, 64));
        const float e = __expf(s - m);
        float sum = e;
        #pragma unroll
        for (int off = 32; off >= 1; off >>= 1) sum += __shfl_xor(sum, off, 64);
        at[lane] = e / sum;
    }
    __syncthreads();

    {
        const int c2 = t * 2;
        float a0 = 0.f, a1 = 0.f;
        #pragma unroll 8
        for (int k = 0; k < 64; ++k) {
            const float ak = at[k];
            const float2 e = *(const float2*)(entW + (size_t)tails[k] * 512 + c2);
            a0 = fmaf(ak, e.x, a0);
            a1 = fmaf(ak, e.y, a1);
        }
        float* o = cat + (size_t)d * 1024;
        *(float2*)&o[c2] = make_float2(a0, a1);
        const float2 de = *(const float2*)(drugW + (size_t)rd * 512 + c2);
        *(float2*)&o[512 + c2] = de;
    }
}

// ---------------------------------------------------------------------------
// gemm_h v3: out[572][512] = ReLU(cat @ linW + b). (unchanged)
// ---------------------------------------------------------------------------
__global__ __launch_bounds__(512) void gemm_h(
    const float* __restrict__ A, const float* __restrict__ linP,
    const float* __restrict__ bias, float* __restrict__ out)
{
    __shared__ float red[8][8][128];      // 32 KB
    const int t = threadIdx.x;
    const int wv = t >> 6, lane = t & 63;
    const int r0 = blockIdx.x * 8;
    const int half = lane >> 5;           // which 64-col linP panel of the pair
    const int cw = (lane * 2) & 63;       // col within panel (even)

    const float* wp = linP + ((size_t)(blockIdx.y * 2 + half) * 256 + wv * 32) * 256
                    + cw * 4;
    const float* ap[8];
    #pragma unroll
    for (int r = 0; r < 8; ++r)
        ap[r] = A + (size_t)min(r0 + r, N_DRUG - 1) * 1024 + wv * 128;

    float acc0[8] = {0.f, 0.f, 0.f, 0.f, 0.f, 0.f, 0.f, 0.f};
    float acc1[8] = {0.f, 0.f, 0.f, 0.f, 0.f, 0.f, 0.f, 0.f};
    #pragma unroll 2
    for (int k4 = 0; k4 < 32; ++k4) {
        const float4 w0 = *(const float4*)(wp + (size_t)k4 * 256);
        const float4 w1 = *(const float4*)(wp + (size_t)k4 * 256 + 4);
        #pragma unroll
        for (int r = 0; r < 8; ++r) {
            const float4 a = *(const float4*)(ap[r] + k4 * 4);   // wave-uniform bcast
            acc0[r] = fmaf(a.x, w0.x, acc0[r]);
            acc0[r] = fmaf(a.y, w0.y, acc0[r]);
            acc0[r] = fmaf(a.z, w0.z, acc0[r]);
            acc0[r] = fmaf(a.w, w0.w, acc0[r]);
            acc1[r] = fmaf(a.x, w1.x, acc1[r]);
            acc1[r] = fmaf(a.y, w1.y, acc1[r]);
            acc1[r] = fmaf(a.z, w1.z, acc1[r]);
            acc1[r] = fmaf(a.w, w1.w, acc1[r]);
        }
    }
    #pragma unroll
    for (int r = 0; r < 8; ++r)
        *(float2*)&red[wv][r][lane * 2] = make_float2(acc0[r], acc1[r]);
    __syncthreads();

    #pragma unroll
    for (int u = 0; u < 2; ++u) {
        const int o = u * 512 + t;
        const int r = o >> 7, cc = o & 127;
        if (r0 + r < N_DRUG) {
            float v = red[0][r][cc];
            #pragma unroll
            for (int w = 1; w < 8; ++w) v += red[w][r][cc];
            v += bias[blockIdx.y * 128 + cc];
            out[(size_t)(r0 + r) * 512 + blockIdx.y * 128 + cc] = fmaxf(v, 0.f);
        }
    }
}

// ---------------------------------------------------------------------------
// scan v3: ONE WAVE PER BLOCK, 2 cols per block, 256 blocks (all CUs).
// Theory: v1/v2 were LDS-issue-bound (8 waves x ~16 LDS instr/round on one
// CU's LDS pipe ~ 1000 cy/round). One wave/CU cuts per-CU LDS pressure 8x;
// critical path becomes the true serial chain write(g)->gather(g+1).
// Lane map: j = lane>>2 (16 node slots), hh = (lane>>1)&1 (neighbor half),
// cl = lane&1 (col). Zero __syncthreads in the whole kernel (single wave).
// BN stats via in-wave shfl butterfly. offs pre-scaled by FS=3.
// ---------------------------------------------------------------------------
__global__ __launch_bounds__(64) void scan_kernel(
    float* hout, const float* __restrict__ gamma, const float* __restrict__ beta,
    const int* __restrict__ nbr_idx, const int* __restrict__ nbr_deg,
    const int* __restrict__ epoch)
{
    __shared__ float fs[(N_DRUG + 1) * FS];      // row N_DRUG = zeros (dummy)
    __shared__ alignas(16) unsigned short offs[N_DRUG * MAXDEG];  // row*FS
    __shared__ float2 ivw[N_DRUG];               // (0.5/deg, 0.5) or (0,1)
    __shared__ int   mxs[N_DRUG];                // max lower-dep row, -1 if none

    const int lane = threadIdx.x;      // 0..63
    const int col  = lane & 1;         // local col 0..1
    const int rg   = lane >> 1;        // staging row-group 0..31
    const int c0   = blockIdx.x * 2;

    // ---- phase 0a: padded, pre-scaled u16 neighbor table; mx; ivw ----
    for (int i = lane; i < N_DRUG; i += 64) {
        const int d = nbr_deg[i];
        ivw[i] = (d > 0) ? make_float2(0.5f / (float)d, 0.5f) : make_float2(0.f, 1.f);
        const int4* np = (const int4*)&nbr_idx[i * MAXDEG];
        uint2* op = (uint2*)&offs[i * MAXDEG];
        int mx = -1;
        #pragma unroll
        for (int u = 0; u < 8; ++u) {
            int4 qq = np[u];
            const int b = u * 4;
            qq.x = (b + 0 < d) ? qq.x : N_DRUG;
            qq.y = (b + 1 < d) ? qq.y : N_DRUG;
            qq.z = (b + 2 < d) ? qq.z : N_DRUG;
            qq.w = (b + 3 < d) ? qq.w : N_DRUG;
            mx = max(mx, (qq.x < i) ? qq.x : -1);
            mx = max(mx, (qq.y < i) ? qq.y : -1);
            mx = max(mx, (qq.z < i) ? qq.z : -1);
            mx = max(mx, (qq.w < i) ? qq.w : -1);
            op[u] = make_uint2((unsigned)(qq.x * FS) | ((unsigned)(qq.y * FS) << 16),
                               (unsigned)(qq.z * FS) | ((unsigned)(qq.w * FS) << 16));
        }
        mxs[i] = mx;
    }

    // ---- phase 0b: stage fs; in-wave BN stats ----
    float sl = 0.f, ql = 0.f;
    for (int r = rg; r < N_DRUG; r += 32) {
        const float v = hout[(size_t)r * DIM + c0 + col];
        fs[r * FS + col] = v;
        sl += v;
        ql = fmaf(v, v, ql);
    }
    if (lane < FS) fs[N_DRUG * FS + lane] = 0.f;
    // butterfly over bits 1..5 (keeps bit0 = col): every lane gets its col's total
    #pragma unroll
    for (int off = 2; off <= 32; off <<= 1) {
        sl += __shfl_xor(sl, off, 64);
        ql += __shfl_xor(ql, off, 64);
    }
    const float mean = sl * (1.f / N_DRUG);
    const float var  = ql * (1.f / N_DRUG) - mean * mean;
    const float rstd = rsqrtf(var + 1e-5f);
    const float scl  = gamma[c0 + col] * rstd;
    const float shf  = beta[c0 + col] - mean * scl;

    // ---- BN apply (same lane mapping as staging) ----
    for (int r = rg; r < N_DRUG; r += 32)
        fs[r * FS + col] = fmaf(fs[r * FS + col], scl, shf);

    // ---- rounds: single-wave serial loop, zero barriers ----
    if (epoch[0] > 1) {
        const int j  = lane >> 2;          // node slot 0..15
        const int hh = (lane >> 1) & 1;    // neighbor half
        const int cl = lane & 1;           // col

        int gs = 0;
        int ge;
        {
            const int jj = 1 + lane;
            const bool flag = (lane >= 15) || (jj >= N_DRUG) ||
                              (mxs[min(jj, N_DRUG - 1)] >= 0);
            ge = 1 + (int)__builtin_ctzll(__ballot(flag) & 0xFFFFULL);
        }
        uint4 ca, cb;
        {
            const uint4* p = (const uint4*)&offs[j * MAXDEG + hh * 16];
            ca = p[0]; cb = p[1];
        }
        while (gs < N_DRUG) {
            const bool pred = (gs + j) < ge;
            float s0 = 0.f, s1 = 0.f;
#define G2(W) { s0 += fs[(W & 0xffffu) + cl]; s1 += fs[(W >> 16) + cl]; }
            if (pred) { G2(ca.x) G2(ca.y) G2(ca.z) G2(ca.w)
                        G2(cb.x) G2(cb.y) G2(cb.z) G2(cb.w) }
#undef G2
            uint4 na, nb;
            {
                const uint4* p = (const uint4*)&offs[min(ge + j, N_DRUG - 1) * MAXDEG + hh * 16];
                na = p[0]; nb = p[1];
            }
            int genext;
            {
                const int jj = ge + 1 + lane;
                const bool flag = (lane >= 15) || (jj >= N_DRUG) ||
                                  (mxs[min(jj, N_DRUG - 1)] >= ge);
                genext = ge + 1 + (int)__builtin_ctzll(__ballot(flag) & 0xFFFFULL);
            }
            float nv = 0.f;
            if (pred) {
                const float cur = fs[(gs + j) * FS + cl];
                const float2 iw = ivw[gs + j];
                float sh = s0 + s1;
                sh += __shfl_xor(sh, 2, 64);     // combine the two halves
                nv = fmaf(sh, iw.x, cur * iw.y);
            }
            asm volatile("" ::: "memory");       // reads stay before the write
            if (pred && hh == 0) fs[(gs + j) * FS + cl] = nv;
            asm volatile("" ::: "memory");       // write stays before next reads
            gs = ge;
            ge = genext;
            ca = na; cb = nb;
        }
    }

    // ---- write back (same wave: program order guarantees rounds done) ----
    for (int r = rg; r < N_DRUG; r += 32)
        hout[(size_t)r * DIM + c0 + col] = fs[r * FS + col];
}

extern "C" void kernel_launch(void* const* d_in, const int* in_sizes, int n_in,
                              void* d_out, int out_size, void* d_ws, size_t ws_size,
                              hipStream_t stream)
{
    const float* drugW = (const float*)d_in[0];
    const float* relaW = (const float*)d_in[1];
    const float* entW  = (const float*)d_in[2];
    const float* Wa    = (const float*)d_in[3];
    const float* linW  = (const float*)d_in[4];
    const float* linb  = (const float*)d_in[5];
    const float* gamma = (const float*)d_in[6];
    const float* beta  = (const float*)d_in[7];
    const int* drug_name = (const int*)d_in[8];
    const int* adj_tail  = (const int*)d_in[9];
    const int* adj_rel   = (const int*)d_in[10];
    const int* nbr_idx   = (const int*)d_in[11];
    const int* nbr_deg   = (const int*)d_in[12];
    const int* epoch     = (const int*)d_in[13];

    float* out = (float*)d_out;    // h lives in d_out; scan updates in place

    // workspace layout (16B-aligned):
    //   linP : 1024*512*4 = 2,097,152   @ 0
    //   relaP:  200*512*4 =   409,600   @ 2,097,152
    //   cat  : 572*1024*4 = 2,342,912   @ 2,506,752   (total ~4.85 MB)
    float* linP  = (float*)d_ws;
    float* relaP = (float*)((char*)d_ws + 2097152);
    float* cat   = (float*)((char*)d_ws + 2506752);

    prep_kernel<<<928, 256, 0, stream>>>(Wa, relaW, linW, linP, relaP);
    attn_kernel<<<N_DRUG, 256, 0, stream>>>(drugW, relaP, entW, drug_name,
                                            adj_tail, adj_rel, cat);
    gemm_h<<<dim3(72, 4), 512, 0, stream>>>(cat, linP, linb, out);
    scan_kernel<<<256, 64, 0, stream>>>(out, gamma, beta, nbr_idx, nbr_deg, epoch);
}

// Round 7
// 223.975 us; speedup vs baseline: 1.0366x; 1.0366x over previous
//
#include <hip/hip_runtime.h>

#define N_DRUG 572
#define DIM 512
#define MAXDEG 32
#define FSB 12           // scan fs row stride in BYTES (2 cols + 1 pad float)

// ---------------------------------------------------------------------------
// prep_kernel: one launch, three independent jobs split by block range.
//  blocks [0,512):   pack linW (1024x512) into K-major panels linP.
//  blocks [512,928): relaP[200][512] = relaW @ Wa^T.  score = drugE . relaP[rel]
//  block 928:        smoothing-scan group schedule (depends only on graph):
//                    sched_g[0]=0, sched_g[r]=group starts, sentinels N_DRUG.
//                    Moves the serial ballot loop OFF the scan critical path.
// ---------------------------------------------------------------------------
__global__ __launch_bounds__(256) void prep_kernel(
    const float* __restrict__ Wa, const float* __restrict__ relaW,
    const float* __restrict__ linW, const int* __restrict__ nbr_idx,
    const int* __restrict__ nbr_deg, float* __restrict__ linP,
    float* __restrict__ relaP, int* __restrict__ sched_g)
{
    const int b = blockIdx.x;
    const int t = threadIdx.x;
    if (b < 512) {                          // ---- pack linW ----
        const int g = b * 256 + t;          // [0,131072)
        const int c = g & 511, k4 = g >> 9; // k4 in [0,256)
        const float4 v = make_float4(linW[(size_t)(k4 * 4 + 0) * 512 + c],
                                     linW[(size_t)(k4 * 4 + 1) * 512 + c],
                                     linW[(size_t)(k4 * 4 + 2) * 512 + c],
                                     linW[(size_t)(k4 * 4 + 3) * 512 + c]);
        *(float4*)&linP[((size_t)(c >> 6) * 256 + k4) * 256 + (c & 63) * 4] = v;
        return;
    }
    if (b == 928) {                         // ---- scan group schedule ----
        __shared__ int mxs2[N_DRUG];
        for (int i = t; i < N_DRUG; i += 256) {
            const int d = nbr_deg[i];
            const int4* np = (const int4*)&nbr_idx[i * MAXDEG];
            int mx = -1;
            #pragma unroll
            for (int u = 0; u < 8; ++u) {
                const int4 qq = np[u];
                const int bb = u * 4;
                mx = max(mx, (bb + 0 < d && qq.x < i) ? qq.x : -1);
                mx = max(mx, (bb + 1 < d && qq.y < i) ? qq.y : -1);
                mx = max(mx, (bb + 2 < d && qq.z < i) ? qq.z : -1);
                mx = max(mx, (bb + 3 < d && qq.w < i) ? qq.w : -1);
            }
            mxs2[i] = mx;
        }
        __syncthreads();
        if (t < 64) {
            int gs = 0, nr = 0;
            if (t == 0) sched_g[0] = 0;
            while (gs < N_DRUG) {
                const int jj = gs + 1 + t;
                const bool flag = (t >= 15) || (jj >= N_DRUG) ||
                                  (mxs2[min(jj, N_DRUG - 1)] >= gs);
                const int ge = gs + 1 + (int)__builtin_ctzll(__ballot(flag) & 0xFFFFULL);
                ++nr;
                if (t == 0) sched_g[nr] = ge;
                gs = ge;
            }
            if (t == 0) {
                sched_g[nr + 1] = N_DRUG;
                sched_g[nr + 2] = N_DRUG;
                sched_g[nr + 3] = N_DRUG;
            }
        }
        return;
    }
    // ---- relaP = relaW @ Wa^T ----
    const int bb = b - 512;                 // [0,416): 13 r-groups x 32 k-panels
    const int rb = bb >> 5, kb = bb & 31;
    const int wv = t >> 6, l = t & 63;
    const int r0 = rb * 16 + wv * 4;        // 4 rows per wave
    const int k0 = kb * 16;                 // 16 output cols per wave

    float a[4][8];
    #pragma unroll
    for (int rr = 0; rr < 4; ++rr) {
        const float4* ap = (const float4*)(relaW + (size_t)min(r0 + rr, 199) * 512 + l * 8);
        const float4 x = ap[0], y = ap[1];
        a[rr][0] = x.x; a[rr][1] = x.y; a[rr][2] = x.z; a[rr][3] = x.w;
        a[rr][4] = y.x; a[rr][5] = y.y; a[rr][6] = y.z; a[rr][7] = y.w;
    }
    float acc[64];
    #pragma unroll
    for (int i = 0; i < 64; ++i) acc[i] = 0.f;
    #pragma unroll
    for (int kk = 0; kk < 16; ++kk) {       // full unroll: acc index compile-time
        const float4* bp = (const float4*)(Wa + (size_t)(k0 + kk) * 512 + l * 8);
        const float4 x = bp[0], y = bp[1];
        const float bv[8] = {x.x, x.y, x.z, x.w, y.x, y.y, y.z, y.w};
        #pragma unroll
        for (int rr = 0; rr < 4; ++rr) {
            float s = acc[rr * 16 + kk];
            #pragma unroll
            for (int j = 0; j < 8; ++j) s = fmaf(a[rr][j], bv[j], s);
            acc[rr * 16 + kk] = s;
        }
    }
    #pragma unroll
    for (int off = 1; off <= 32; off <<= 1) {
        #pragma unroll
        for (int i = 0; i < 64; ++i) acc[i] += __shfl_xor(acc[i], off, 64);
    }
    float outv = acc[0];
    #pragma unroll
    for (int i = 1; i < 64; ++i) outv = (l == i) ? acc[i] : outv;
    const int rr = l >> 4, kk = l & 15;
    if (r0 + rr < 200) relaP[(size_t)(r0 + rr) * 512 + k0 + kk] = outv;
}

// ---------------------------------------------------------------------------
// attn_kernel: one block per drug. scores (vs relaP) -> softmax -> agg gather.
// Writes cat[d] = [agg | drug_e]. (unchanged)
// ---------------------------------------------------------------------------
__global__ __launch_bounds__(256) void attn_kernel(
    const float* __restrict__ drugW, const float* __restrict__ relaP,
    const float* __restrict__ entW, const int* __restrict__ dn,
    const int* __restrict__ adj_tail, const int* __restrict__ adj_rel,
    float* __restrict__ cat)
{
    __shared__ float at[64];
    __shared__ int tails[64];
    __shared__ int rels[64];
    const int d = blockIdx.x;
    const int t = threadIdx.x;
    const int w = t >> 6, lane = t & 63;

    if (t < 64) {
        tails[t] = adj_tail[d * 64 + t];
        rels[t]  = adj_rel[d * 64 + t];
    }
    const int rd = dn[d];
    float qv[8];
    {
        const float4* qp = (const float4*)(drugW + (size_t)rd * 512 + lane * 8);
        const float4 x = qp[0], y = qp[1];
        qv[0] = x.x; qv[1] = x.y; qv[2] = x.z; qv[3] = x.w;
        qv[4] = y.x; qv[5] = y.y; qv[6] = y.z; qv[7] = y.w;
    }
    __syncthreads();

    #pragma unroll 4
    for (int kk = 0; kk < 16; ++kk) {
        const int k = w * 16 + kk;
        const float4* p = (const float4*)(relaP + (size_t)rels[k] * 512 + lane * 8);
        const float4 x = p[0], y = p[1];
        float s = 0.f;
        s = fmaf(qv[0], x.x, s); s = fmaf(qv[1], x.y, s);
        s = fmaf(qv[2], x.z, s); s = fmaf(qv[3], x.w, s);
        s = fmaf(qv[4], y.x, s); s = fmaf(qv[5], y.y, s);
        s = fmaf(qv[6], y.z, s); s = fmaf(qv[7], y.w, s);
        #pragma unroll
        for (int off = 32; off >= 1; off >>= 1) s += __shfl_xor(s, off, 64);
        if (lane == 0) at[k] = s * 0.0441941738241592f;   // 1/sqrt(512)
    }
    __syncthreads();

    if (w == 0) {
        const float s = at[lane];
        float m = s;
        #pragma unroll
        for (int off = 32; off >= 1; off >>= 1) m = fmaxf(m, __shfl_xor(m, off, 64));
        const float e = __expf(s - m);
        float sum = e;
        #pragma unroll
        for (int off = 32; off >= 1; off >>= 1) sum += __shfl_xor(sum, off, 64);
        at[lane] = e / sum;
    }
    __syncthreads();

    {
        const int c2 = t * 2;
        float a0 = 0.f, a1 = 0.f;
        #pragma unroll 8
        for (int k = 0; k < 64; ++k) {
            const float ak = at[k];
            const float2 e = *(const float2*)(entW + (size_t)tails[k] * 512 + c2);
            a0 = fmaf(ak, e.x, a0);
            a1 = fmaf(ak, e.y, a1);
        }
        float* o = cat + (size_t)d * 1024;
        *(float2*)&o[c2] = make_float2(a0, a1);
        const float2 de = *(const float2*)(drugW + (size_t)rd * 512 + c2);
        *(float2*)&o[512 + c2] = de;
    }
}

// ---------------------------------------------------------------------------
// gemm_h v3: out[572][512] = ReLU(cat @ linW + b). (unchanged)
// ---------------------------------------------------------------------------
__global__ __launch_bounds__(512) void gemm_h(
    const float* __restrict__ A, const float* __restrict__ linP,
    const float* __restrict__ bias, float* __restrict__ out)
{
    __shared__ float red[8][8][128];      // 32 KB
    const int t = threadIdx.x;
    const int wv = t >> 6, lane = t & 63;
    const int r0 = blockIdx.x * 8;
    const int half = lane >> 5;           // which 64-col linP panel of the pair
    const int cw = (lane * 2) & 63;       // col within panel (even)

    const float* wp = linP + ((size_t)(blockIdx.y * 2 + half) * 256 + wv * 32) * 256
                    + cw * 4;
    const float* ap[8];
    #pragma unroll
    for (int r = 0; r < 8; ++r)
        ap[r] = A + (size_t)min(r0 + r, N_DRUG - 1) * 1024 + wv * 128;

    float acc0[8] = {0.f, 0.f, 0.f, 0.f, 0.f, 0.f, 0.f, 0.f};
    float acc1[8] = {0.f, 0.f, 0.f, 0.f, 0.f, 0.f, 0.f, 0.f};
    #pragma unroll 2
    for (int k4 = 0; k4 < 32; ++k4) {
        const float4 w0 = *(const float4*)(wp + (size_t)k4 * 256);
        const float4 w1 = *(const float4*)(wp + (size_t)k4 * 256 + 4);
        #pragma unroll
        for (int r = 0; r < 8; ++r) {
            const float4 a = *(const float4*)(ap[r] + k4 * 4);   // wave-uniform bcast
            acc0[r] = fmaf(a.x, w0.x, acc0[r]);
            acc0[r] = fmaf(a.y, w0.y, acc0[r]);
            acc0[r] = fmaf(a.z, w0.z, acc0[r]);
            acc0[r] = fmaf(a.w, w0.w, acc0[r]);
            acc1[r] = fmaf(a.x, w1.x, acc1[r]);
            acc1[r] = fmaf(a.y, w1.y, acc1[r]);
            acc1[r] = fmaf(a.z, w1.z, acc1[r]);
            acc1[r] = fmaf(a.w, w1.w, acc1[r]);
        }
    }
    #pragma unroll
    for (int r = 0; r < 8; ++r)
        *(float2*)&red[wv][r][lane * 2] = make_float2(acc0[r], acc1[r]);
    __syncthreads();

    #pragma unroll
    for (int u = 0; u < 2; ++u) {
        const int o = u * 512 + t;
        const int r = o >> 7, cc = o & 127;
        if (r0 + r < N_DRUG) {
            float v = red[0][r][cc];
            #pragma unroll
            for (int w = 1; w < 8; ++w) v += red[w][r][cc];
            v += bias[blockIdx.y * 128 + cc];
            out[(size_t)(r0 + r) * 512 + blockIdx.y * 128 + cc] = fmaxf(v, 0.f);
        }
    }
}

// ---------------------------------------------------------------------------
// scan v4: one wave per block, 2 cols, 256 blocks. Minimal round body:
//  - group schedule PRECOMPUTED in prep (sched_g): one broadcast LDS read
//    replaces mxs-read + ballot + ctz per round.
//  - cur/ivw prefetched one round ahead (rows [ge,genext) are not written in
//    round r, so the prefetch is race-free).
//  - DPP quad_perm[2,3,0,1] (= lane xor 2 = hh partner, same col) replaces
//    __shfl_xor: VALU-speed, removes ~120cy LDS latency from the chain.
//  - offs tables store BYTE offsets (row*12) with the col shift pre-added
//    (offsA=+0, offsB=+4): gather addr = W & 0xffff, no shifts/adds.
// ---------------------------------------------------------------------------
__global__ __launch_bounds__(64) void scan_kernel(
    float* hout, const float* __restrict__ gamma, const float* __restrict__ beta,
    const int* __restrict__ nbr_idx, const int* __restrict__ nbr_deg,
    const int* __restrict__ epoch, const int* __restrict__ sched_g)
{
    __shared__ alignas(16) unsigned char fsb[(N_DRUG + 1) * FSB];     // 6876 B
    __shared__ alignas(16) unsigned short offsA[N_DRUG * MAXDEG];     // 36.6 KB
    __shared__ alignas(16) unsigned short offsB[N_DRUG * MAXDEG];     // 36.6 KB
    __shared__ float2 ivw[N_DRUG];                                    // 4.6 KB
    __shared__ int sched[N_DRUG + 8];                                 // 2.3 KB

    const int lane = threadIdx.x;      // 0..63
    const int col  = lane & 1;         // local col 0..1
    const int rg   = lane >> 1;        // staging row-group 0..31
    const int c0   = blockIdx.x * 2;
    const int cl4  = col * 4;

    // ---- load precomputed schedule ----
    for (int i = lane; i < N_DRUG + 8; i += 64) sched[i] = sched_g[i];

    // ---- padded, byte-prescaled neighbor tables (per-col variants); ivw ----
    for (int i = lane; i < N_DRUG; i += 64) {
        const int d = nbr_deg[i];
        ivw[i] = (d > 0) ? make_float2(0.5f / (float)d, 0.5f) : make_float2(0.f, 1.f);
        const int4* np = (const int4*)&nbr_idx[i * MAXDEG];
        uint2* opA = (uint2*)&offsA[i * MAXDEG];
        uint2* opB = (uint2*)&offsB[i * MAXDEG];
        #pragma unroll
        for (int u = 0; u < 8; ++u) {
            const int4 qq = np[u];
            const int b = u * 4;
            const int rx = (b + 0 < d) ? qq.x : N_DRUG;
            const int ry = (b + 1 < d) ? qq.y : N_DRUG;
            const int rz = (b + 2 < d) ? qq.z : N_DRUG;
            const int rw = (b + 3 < d) ? qq.w : N_DRUG;
            const unsigned w0 = (unsigned)(rx * FSB) | ((unsigned)(ry * FSB) << 16);
            const unsigned w1 = (unsigned)(rz * FSB) | ((unsigned)(rw * FSB) << 16);
            opA[u] = make_uint2(w0, w1);
            opB[u] = make_uint2(w0 + 0x00040004u, w1 + 0x00040004u);
        }
    }

    // ---- stage fs; in-wave BN stats ----
    float sl = 0.f, ql = 0.f;
    for (int r = rg; r < N_DRUG; r += 32) {
        const float v = hout[(size_t)r * DIM + c0 + col];
        *(float*)(fsb + r * FSB + cl4) = v;
        sl += v;
        ql = fmaf(v, v, ql);
    }
    if (lane < 3) *(float*)(fsb + N_DRUG * FSB + lane * 4) = 0.f;   // dummy row
    #pragma unroll
    for (int off = 2; off <= 32; off <<= 1) {   // keep bit0 = col
        sl += __shfl_xor(sl, off, 64);
        ql += __shfl_xor(ql, off, 64);
    }
    const float mean = sl * (1.f / N_DRUG);
    const float var  = ql * (1.f / N_DRUG) - mean * mean;
    const float rstd = rsqrtf(var + 1e-5f);
    const float scl  = gamma[c0 + col] * rstd;
    const float shf  = beta[c0 + col] - mean * scl;

    // ---- BN apply ----
    for (int r = rg; r < N_DRUG; r += 32) {
        float* p = (float*)(fsb + r * FSB + cl4);
        *p = fmaf(*p, scl, shf);
    }

    // ---- rounds: single-wave, schedule-driven, fully prefetched ----
    if (epoch[0] > 1) {
        const int j  = lane >> 2;          // node slot 0..15
        const int hh = (lane >> 1) & 1;    // neighbor half
        const unsigned short* obase = col ? offsB : offsA;

        int gs  = 0;                       // = sched[0]
        int ge  = sched[1];
        int ge2 = sched[2];
        int rp  = 3;                       // next sched prefetch index
        uint4 ca, cb;
        {
            const uint4* p = (const uint4*)&obase[j * MAXDEG + hh * 16];
            ca = p[0]; cb = p[1];
        }
        float  cur = *(const float*)(fsb + j * FSB + cl4);
        float2 iw  = ivw[j];

        while (gs < N_DRUG) {
            const bool pred = (gs + j) < ge;
            float s0 = 0.f, s1 = 0.f;
            if (pred) {
#define G2(W) { s0 += *(const float*)(fsb + (W & 0xffffu)); \
                s1 += *(const float*)(fsb + (W >> 16)); }
                G2(ca.x) G2(ca.y) G2(ca.z) G2(ca.w)
                G2(cb.x) G2(cb.y) G2(cb.z) G2(cb.w)
#undef G2
            }
            // prefetch next round's state (rows >= ge: not written this round)
            uint4 na, nb;
            {
                const uint4* p = (const uint4*)&obase[min(ge + j, N_DRUG - 1) * MAXDEG + hh * 16];
                na = p[0]; nb = p[1];
            }
            const float  ncur = *(const float*)(fsb + min(ge + j, N_DRUG) * FSB + cl4);
            const float2 niw  = ivw[min(ge + j, N_DRUG - 1)];
            const int    nge  = sched[rp];

            float nv = 0.f;
            if (pred) {
                float sh = s0 + s1;
                // combine hh halves: DPP quad_perm [2,3,0,1] == lane xor 2
                sh += __int_as_float(__builtin_amdgcn_mov_dpp(
                          __float_as_int(sh), 0x4E, 0xF, 0xF, false));
                nv = fmaf(sh, iw.x, cur * iw.y);
            }
            asm volatile("" ::: "memory");       // reads stay before the write
            if (pred && hh == 0) *(float*)(fsb + (gs + j) * FSB + cl4) = nv;
            asm volatile("" ::: "memory");       // write stays before next reads
            gs = ge; ge = ge2; ge2 = nge; ++rp;
            ca = na; cb = nb; cur = ncur; iw = niw;
        }
    }

    // ---- write back (same wave: program order guarantees rounds done) ----
    for (int r = rg; r < N_DRUG; r += 32)
        hout[(size_t)r * DIM + c0 + col] = *(const float*)(fsb + r * FSB + cl4);
}

extern "C" void kernel_launch(void* const* d_in, const int* in_sizes, int n_in,
                              void* d_out, int out_size, void* d_ws, size_t ws_size,
                              hipStream_t stream)
{
    const float* drugW = (const float*)d_in[0];
    const float* relaW = (const float*)d_in[1];
    const float* entW  = (const float*)d_in[2];
    const float* Wa    = (const float*)d_in[3];
    const float* linW  = (const float*)d_in[4];
    const float* linb  = (const float*)d_in[5];
    const float* gamma = (const float*)d_in[6];
    const float* beta  = (const float*)d_in[7];
    const int* drug_name = (const int*)d_in[8];
    const int* adj_tail  = (const int*)d_in[9];
    const int* adj_rel   = (const int*)d_in[10];
    const int* nbr_idx   = (const int*)d_in[11];
    const int* nbr_deg   = (const int*)d_in[12];
    const int* epoch     = (const int*)d_in[13];

    float* out = (float*)d_out;    // h lives in d_out; scan updates in place

    // workspace layout (16B-aligned):
    //   linP  : 1024*512*4 = 2,097,152   @ 0
    //   relaP :  200*512*4 =   409,600   @ 2,097,152
    //   cat   : 572*1024*4 = 2,342,912   @ 2,506,752
    //   sched : 580*4      =     2,320   @ 4,849,664   (total ~4.86 MB)
    float* linP   = (float*)d_ws;
    float* relaP  = (float*)((char*)d_ws + 2097152);
    float* cat    = (float*)((char*)d_ws + 2506752);
    int*   sched  = (int*)  ((char*)d_ws + 4849664);

    prep_kernel<<<929, 256, 0, stream>>>(Wa, relaW, linW, nbr_idx, nbr_deg,
                                         linP, relaP, sched);
    attn_kernel<<<N_DRUG, 256, 0, stream>>>(drugW, relaP, entW, drug_name,
                                            adj_tail, adj_rel, cat);
    gemm_h<<<dim3(72, 4), 512, 0, stream>>>(cat, linP, linb, out);
    scan_kernel<<<256, 64, 0, stream>>>(out, gamma, beta, nbr_idx, nbr_deg,
                                        epoch, sched);
}

// Round 8
// 223.958 us; speedup vs baseline: 1.0367x; 1.0001x over previous
//
#include <hip/hip_runtime.h>

#define N_DRUG 572
#define DIM 512
#define MAXDEG 32
#define FSB 12           // scan fs row stride in BYTES (2 cols + 1 pad float)

// ---------------------------------------------------------------------------
// prep_kernel: one launch, three independent jobs split by block range.
//  blocks [0,512):   pack linW (1024x512) into K-major panels linP.
//  blocks [512,928): relaP[200][512] = relaW @ Wa^T.  score = drugE . relaP[rel]
//  block 928:        smoothing-scan group schedule (graph-only dependent).
// ---------------------------------------------------------------------------
__global__ __launch_bounds__(256) void prep_kernel(
    const float* __restrict__ Wa, const float* __restrict__ relaW,
    const float* __restrict__ linW, const int* __restrict__ nbr_idx,
    const int* __restrict__ nbr_deg, float* __restrict__ linP,
    float* __restrict__ relaP, int* __restrict__ sched_g)
{
    const int b = blockIdx.x;
    const int t = threadIdx.x;
    if (b < 512) {                          // ---- pack linW ----
        const int g = b * 256 + t;          // [0,131072)
        const int c = g & 511, k4 = g >> 9; // k4 in [0,256)
        const float4 v = make_float4(linW[(size_t)(k4 * 4 + 0) * 512 + c],
                                     linW[(size_t)(k4 * 4 + 1) * 512 + c],
                                     linW[(size_t)(k4 * 4 + 2) * 512 + c],
                                     linW[(size_t)(k4 * 4 + 3) * 512 + c]);
        *(float4*)&linP[((size_t)(c >> 6) * 256 + k4) * 256 + (c & 63) * 4] = v;
        return;
    }
    if (b == 928) {                         // ---- scan group schedule ----
        __shared__ int mxs2[N_DRUG];
        for (int i = t; i < N_DRUG; i += 256) {
            const int d = nbr_deg[i];
            const int4* np = (const int4*)&nbr_idx[i * MAXDEG];
            int mx = -1;
            #pragma unroll
            for (int u = 0; u < 8; ++u) {
                const int4 qq = np[u];
                const int bb = u * 4;
                mx = max(mx, (bb + 0 < d && qq.x < i) ? qq.x : -1);
                mx = max(mx, (bb + 1 < d && qq.y < i) ? qq.y : -1);
                mx = max(mx, (bb + 2 < d && qq.z < i) ? qq.z : -1);
                mx = max(mx, (bb + 3 < d && qq.w < i) ? qq.w : -1);
            }
            mxs2[i] = mx;
        }
        __syncthreads();
        if (t < 64) {
            int gs = 0, nr = 0;
            if (t == 0) sched_g[0] = 0;
            while (gs < N_DRUG) {
                const int jj = gs + 1 + t;
                const bool flag = (t >= 15) || (jj >= N_DRUG) ||
                                  (mxs2[min(jj, N_DRUG - 1)] >= gs);
                const int ge = gs + 1 + (int)__builtin_ctzll(__ballot(flag) & 0xFFFFULL);
                ++nr;
                if (t == 0) sched_g[nr] = ge;
                gs = ge;
            }
            if (t == 0) {
                sched_g[nr + 1] = N_DRUG;
                sched_g[nr + 2] = N_DRUG;
                sched_g[nr + 3] = N_DRUG;
            }
        }
        return;
    }
    // ---- relaP = relaW @ Wa^T ----
    const int bb = b - 512;                 // [0,416): 13 r-groups x 32 k-panels
    const int rb = bb >> 5, kb = bb & 31;
    const int wv = t >> 6, l = t & 63;
    const int r0 = rb * 16 + wv * 4;        // 4 rows per wave
    const int k0 = kb * 16;                 // 16 output cols per wave

    float a[4][8];
    #pragma unroll
    for (int rr = 0; rr < 4; ++rr) {
        const float4* ap = (const float4*)(relaW + (size_t)min(r0 + rr, 199) * 512 + l * 8);
        const float4 x = ap[0], y = ap[1];
        a[rr][0] = x.x; a[rr][1] = x.y; a[rr][2] = x.z; a[rr][3] = x.w;
        a[rr][4] = y.x; a[rr][5] = y.y; a[rr][6] = y.z; a[rr][7] = y.w;
    }
    float acc[64];
    #pragma unroll
    for (int i = 0; i < 64; ++i) acc[i] = 0.f;
    #pragma unroll
    for (int kk = 0; kk < 16; ++kk) {       // full unroll: acc index compile-time
        const float4* bp = (const float4*)(Wa + (size_t)(k0 + kk) * 512 + l * 8);
        const float4 x = bp[0], y = bp[1];
        const float bv[8] = {x.x, x.y, x.z, x.w, y.x, y.y, y.z, y.w};
        #pragma unroll
        for (int rr = 0; rr < 4; ++rr) {
            float s = acc[rr * 16 + kk];
            #pragma unroll
            for (int j = 0; j < 8; ++j) s = fmaf(a[rr][j], bv[j], s);
            acc[rr * 16 + kk] = s;
        }
    }
    #pragma unroll
    for (int off = 1; off <= 32; off <<= 1) {
        #pragma unroll
        for (int i = 0; i < 64; ++i) acc[i] += __shfl_xor(acc[i], off, 64);
    }
    float outv = acc[0];
    #pragma unroll
    for (int i = 1; i < 64; ++i) outv = (l == i) ? acc[i] : outv;
    const int rr = l >> 4, kk = l & 15;
    if (r0 + rr < 200) relaP[(size_t)(r0 + rr) * 512 + k0 + kk] = outv;
}

// ---------------------------------------------------------------------------
// attn_kernel: one block per drug. scores (vs relaP) -> softmax -> agg gather.
// Writes cat[d] = [agg | drug_e]. (unchanged)
// ---------------------------------------------------------------------------
__global__ __launch_bounds__(256) void attn_kernel(
    const float* __restrict__ drugW, const float* __restrict__ relaP,
    const float* __restrict__ entW, const int* __restrict__ dn,
    const int* __restrict__ adj_tail, const int* __restrict__ adj_rel,
    float* __restrict__ cat)
{
    __shared__ float at[64];
    __shared__ int tails[64];
    __shared__ int rels[64];
    const int d = blockIdx.x;
    const int t = threadIdx.x;
    const int w = t >> 6, lane = t & 63;

    if (t < 64) {
        tails[t] = adj_tail[d * 64 + t];
        rels[t]  = adj_rel[d * 64 + t];
    }
    const int rd = dn[d];
    float qv[8];
    {
        const float4* qp = (const float4*)(drugW + (size_t)rd * 512 + lane * 8);
        const float4 x = qp[0], y = qp[1];
        qv[0] = x.x; qv[1] = x.y; qv[2] = x.z; qv[3] = x.w;
        qv[4] = y.x; qv[5] = y.y; qv[6] = y.z; qv[7] = y.w;
    }
    __syncthreads();

    #pragma unroll 4
    for (int kk = 0; kk < 16; ++kk) {
        const int k = w * 16 + kk;
        const float4* p = (const float4*)(relaP + (size_t)rels[k] * 512 + lane * 8);
        const float4 x = p[0], y = p[1];
        float s = 0.f;
        s = fmaf(qv[0], x.x, s); s = fmaf(qv[1], x.y, s);
        s = fmaf(qv[2], x.z, s); s = fmaf(qv[3], x.w, s);
        s = fmaf(qv[4], y.x, s); s = fmaf(qv[5], y.y, s);
        s = fmaf(qv[6], y.z, s); s = fmaf(qv[7], y.w, s);
        #pragma unroll
        for (int off = 32; off >= 1; off >>= 1) s += __shfl_xor(s, off, 64);
        if (lane == 0) at[k] = s * 0.0441941738241592f;   // 1/sqrt(512)
    }
    __syncthreads();

    if (w == 0) {
        const float s = at[lane];
        float m = s;
        #pragma unroll
        for (int off = 32; off >= 1; off >>= 1) m = fmaxf(m, __shfl_xor(m, off, 64));
        const float e = __expf(s - m);
        float sum = e;
        #pragma unroll
        for (int off = 32; off >= 1; off >>= 1) sum += __shfl_xor(sum, off, 64);
        at[lane] = e / sum;
    }
    __syncthreads();

    {
        const int c2 = t * 2;
        float a0 = 0.f, a1 = 0.f;
        #pragma unroll 8
        for (int k = 0; k < 64; ++k) {
            const float ak = at[k];
            const float2 e = *(const float2*)(entW + (size_t)tails[k] * 512 + c2);
            a0 = fmaf(ak, e.x, a0);
            a1 = fmaf(ak, e.y, a1);
        }
        float* o = cat + (size_t)d * 1024;
        *(float2*)&o[c2] = make_float2(a0, a1);
        const float2 de = *(const float2*)(drugW + (size_t)rd * 512 + c2);
        *(float2*)&o[512 + c2] = de;
    }
}

// ---------------------------------------------------------------------------
// gemm_h v4: out[572][512] = ReLU(cat @ linW + b).
// Same geometry as v3 (grid (72,4) x 512, 8-way split-K, thread = 8 rows x
// 2 cols) but with MANUAL register double-buffering: iteration k4+1's
// 2 W-float4 + 8 A-float4 are loaded into named `next` registers BEFORE
// k4's 64 FMAs issue, then rotated. v3's VGPR=40 showed the compiler kept
// zero loads in flight (full L2 latency exposed per iter); this forces
// ~10 loads in flight during every 128-cy FMA burst by construction.
// ---------------------------------------------------------------------------
__global__ __launch_bounds__(512) void gemm_h(
    const float* __restrict__ A, const float* __restrict__ linP,
    const float* __restrict__ bias, float* __restrict__ out)
{
    __shared__ float red[8][8][128];      // 32 KB
    const int t = threadIdx.x;
    const int wv = t >> 6, lane = t & 63;
    const int r0 = blockIdx.x * 8;
    const int half = lane >> 5;           // which 64-col linP panel of the pair
    const int cw = (lane * 2) & 63;       // col within panel (even)

    const float* wp = linP + ((size_t)(blockIdx.y * 2 + half) * 256 + wv * 32) * 256
                    + cw * 4;
    const float* ap[8];
    #pragma unroll
    for (int r = 0; r < 8; ++r)
        ap[r] = A + (size_t)min(r0 + r, N_DRUG - 1) * 1024 + wv * 128;

    float acc0[8] = {0.f, 0.f, 0.f, 0.f, 0.f, 0.f, 0.f, 0.f};
    float acc1[8] = {0.f, 0.f, 0.f, 0.f, 0.f, 0.f, 0.f, 0.f};

    // prologue: load iteration 0
    float4 wa = *(const float4*)(wp);
    float4 wb = *(const float4*)(wp + 4);
    float4 aa[8];
    #pragma unroll
    for (int r = 0; r < 8; ++r) aa[r] = *(const float4*)(ap[r]);

    for (int k4 = 0; k4 < 32; ++k4) {
        const int kn = (k4 + 1) & 31;     // last iter wraps to 0 (harmless)
        const float4 wan = *(const float4*)(wp + (size_t)kn * 256);
        const float4 wbn = *(const float4*)(wp + (size_t)kn * 256 + 4);
        float4 an[8];
        #pragma unroll
        for (int r = 0; r < 8; ++r) an[r] = *(const float4*)(ap[r] + kn * 4);

        #pragma unroll
        for (int r = 0; r < 8; ++r) {
            const float4 a = aa[r];
            acc0[r] = fmaf(a.x, wa.x, acc0[r]);
            acc0[r] = fmaf(a.y, wa.y, acc0[r]);
            acc0[r] = fmaf(a.z, wa.z, acc0[r]);
            acc0[r] = fmaf(a.w, wa.w, acc0[r]);
            acc1[r] = fmaf(a.x, wb.x, acc1[r]);
            acc1[r] = fmaf(a.y, wb.y, acc1[r]);
            acc1[r] = fmaf(a.z, wb.z, acc1[r]);
            acc1[r] = fmaf(a.w, wb.w, acc1[r]);
        }
        wa = wan; wb = wbn;
        #pragma unroll
        for (int r = 0; r < 8; ++r) aa[r] = an[r];
    }

    #pragma unroll
    for (int r = 0; r < 8; ++r)
        *(float2*)&red[wv][r][lane * 2] = make_float2(acc0[r], acc1[r]);
    __syncthreads();

    #pragma unroll
    for (int u = 0; u < 2; ++u) {
        const int o = u * 512 + t;
        const int r = o >> 7, cc = o & 127;
        if (r0 + r < N_DRUG) {
            float v = red[0][r][cc];
            #pragma unroll
            for (int w = 1; w < 8; ++w) v += red[w][r][cc];
            v += bias[blockIdx.y * 128 + cc];
            out[(size_t)(r0 + r) * 512 + blockIdx.y * 128 + cc] = fmaxf(v, 0.f);
        }
    }
}

// ---------------------------------------------------------------------------
// scan v4: one wave per block, 2 cols, 256 blocks. (unchanged from round 7)
// ---------------------------------------------------------------------------
__global__ __launch_bounds__(64) void scan_kernel(
    float* hout, const float* __restrict__ gamma, const float* __restrict__ beta,
    const int* __restrict__ nbr_idx, const int* __restrict__ nbr_deg,
    const int* __restrict__ epoch, const int* __restrict__ sched_g)
{
    __shared__ alignas(16) unsigned char fsb[(N_DRUG + 1) * FSB];     // 6876 B
    __shared__ alignas(16) unsigned short offsA[N_DRUG * MAXDEG];     // 36.6 KB
    __shared__ alignas(16) unsigned short offsB[N_DRUG * MAXDEG];     // 36.6 KB
    __shared__ float2 ivw[N_DRUG];                                    // 4.6 KB
    __shared__ int sched[N_DRUG + 8];                                 // 2.3 KB

    const int lane = threadIdx.x;      // 0..63
    const int col  = lane & 1;         // local col 0..1
    const int rg   = lane >> 1;        // staging row-group 0..31
    const int c0   = blockIdx.x * 2;
    const int cl4  = col * 4;

    // ---- load precomputed schedule ----
    for (int i = lane; i < N_DRUG + 8; i += 64) sched[i] = sched_g[i];

    // ---- padded, byte-prescaled neighbor tables (per-col variants); ivw ----
    for (int i = lane; i < N_DRUG; i += 64) {
        const int d = nbr_deg[i];
        ivw[i] = (d > 0) ? make_float2(0.5f / (float)d, 0.5f) : make_float2(0.f, 1.f);
        const int4* np = (const int4*)&nbr_idx[i * MAXDEG];
        uint2* opA = (uint2*)&offsA[i * MAXDEG];
        uint2* opB = (uint2*)&offsB[i * MAXDEG];
        #pragma unroll
        for (int u = 0; u < 8; ++u) {
            const int4 qq = np[u];
            const int b = u * 4;
            const int rx = (b + 0 < d) ? qq.x : N_DRUG;
            const int ry = (b + 1 < d) ? qq.y : N_DRUG;
            const int rz = (b + 2 < d) ? qq.z : N_DRUG;
            const int rw = (b + 3 < d) ? qq.w : N_DRUG;
            const unsigned w0 = (unsigned)(rx * FSB) | ((unsigned)(ry * FSB) << 16);
            const unsigned w1 = (unsigned)(rz * FSB) | ((unsigned)(rw * FSB) << 16);
            opA[u] = make_uint2(w0, w1);
            opB[u] = make_uint2(w0 + 0x00040004u, w1 + 0x00040004u);
        }
    }

    // ---- stage fs; in-wave BN stats ----
    float sl = 0.f, ql = 0.f;
    for (int r = rg; r < N_DRUG; r += 32) {
        const float v = hout[(size_t)r * DIM + c0 + col];
        *(float*)(fsb + r * FSB + cl4) = v;
        sl += v;
        ql = fmaf(v, v, ql);
    }
    if (lane < 3) *(float*)(fsb + N_DRUG * FSB + lane * 4) = 0.f;   // dummy row
    #pragma unroll
    for (int off = 2; off <= 32; off <<= 1) {   // keep bit0 = col
        sl += __shfl_xor(sl, off, 64);
        ql += __shfl_xor(ql, off, 64);
    }
    const float mean = sl * (1.f / N_DRUG);
    const float var  = ql * (1.f / N_DRUG) - mean * mean;
    const float rstd = rsqrtf(var + 1e-5f);
    const float scl  = gamma[c0 + col] * rstd;
    const float shf  = beta[c0 + col] - mean * scl;

    // ---- BN apply ----
    for (int r = rg; r < N_DRUG; r += 32) {
        float* p = (float*)(fsb + r * FSB + cl4);
        *p = fmaf(*p, scl, shf);
    }

    // ---- rounds: single-wave, schedule-driven, fully prefetched ----
    if (epoch[0] > 1) {
        const int j  = lane >> 2;          // node slot 0..15
        const int hh = (lane >> 1) & 1;    // neighbor half
        const unsigned short* obase = col ? offsB : offsA;

        int gs  = 0;                       // = sched[0]
        int ge  = sched[1];
        int ge2 = sched[2];
        int rp  = 3;                       // next sched prefetch index
        uint4 ca, cb;
        {
            const uint4* p = (const uint4*)&obase[j * MAXDEG + hh * 16];
            ca = p[0]; cb = p[1];
        }
        float  cur = *(const float*)(fsb + j * FSB + cl4);
        float2 iw  = ivw[j];

        while (gs < N_DRUG) {
            const bool pred = (gs + j) < ge;
            float s0 = 0.f, s1 = 0.f;
            if (pred) {
#define G2(W) { s0 += *(const float*)(fsb + (W & 0xffffu)); \
                s1 += *(const float*)(fsb + (W >> 16)); }
                G2(ca.x) G2(ca.y) G2(ca.z) G2(ca.w)
                G2(cb.x) G2(cb.y) G2(cb.z) G2(cb.w)
#undef G2
            }
            // prefetch next round's state (rows >= ge: not written this round)
            uint4 na, nb;
            {
                const uint4* p = (const uint4*)&obase[min(ge + j, N_DRUG - 1) * MAXDEG + hh * 16];
                na = p[0]; nb = p[1];
            }
            const float  ncur = *(const float*)(fsb + min(ge + j, N_DRUG) * FSB + cl4);
            const float2 niw  = ivw[min(ge + j, N_DRUG - 1)];
            const int    nge  = sched[rp];

            float nv = 0.f;
            if (pred) {
                float sh = s0 + s1;
                // combine hh halves: DPP quad_perm [2,3,0,1] == lane xor 2
                sh += __int_as_float(__builtin_amdgcn_mov_dpp(
                          __float_as_int(sh), 0x4E, 0xF, 0xF, false));
                nv = fmaf(sh, iw.x, cur * iw.y);
            }
            asm volatile("" ::: "memory");       // reads stay before the write
            if (pred && hh == 0) *(float*)(fsb + (gs + j) * FSB + cl4) = nv;
            asm volatile("" ::: "memory");       // write stays before next reads
            gs = ge; ge = ge2; ge2 = nge; ++rp;
            ca = na; cb = nb; cur = ncur; iw = niw;
        }
    }

    // ---- write back (same wave: program order guarantees rounds done) ----
    for (int r = rg; r < N_DRUG; r += 32)
        hout[(size_t)r * DIM + c0 + col] = *(const float*)(fsb + r * FSB + cl4);
}

extern "C" void kernel_launch(void* const* d_in, const int* in_sizes, int n_in,
                              void* d_out, int out_size, void* d_ws, size_t ws_size,
                              hipStream_t stream)
{
    const float* drugW = (const float*)d_in[0];
    const float* relaW = (const float*)d_in[1];
    const float* entW  = (const float*)d_in[2];
    const float* Wa    = (const float*)d_in[3];
    const float* linW  = (const float*)d_in[4];
    const float* linb  = (const float*)d_in[5];
    const float* gamma = (const float*)d_in[6];
    const float* beta  = (const float*)d_in[7];
    const int* drug_name = (const int*)d_in[8];
    const int* adj_tail  = (const int*)d_in[9];
    const int* adj_rel   = (const int*)d_in[10];
    const int* nbr_idx   = (const int*)d_in[11];
    const int* nbr_deg   = (const int*)d_in[12];
    const int* epoch     = (const int*)d_in[13];

    float* out = (float*)d_out;    // h lives in d_out; scan updates in place

    // workspace layout (16B-aligned):
    //   linP  : 1024*512*4 = 2,097,152   @ 0
    //   relaP :  200*512*4 =   409,600   @ 2,097,152
    //   cat   : 572*1024*4 = 2,342,912   @ 2,506,752
    //   sched : 580*4      =     2,320   @ 4,849,664   (total ~4.86 MB)
    float* linP   = (float*)d_ws;
    float* relaP  = (float*)((char*)d_ws + 2097152);
    float* cat    = (float*)((char*)d_ws + 2506752);
    int*   sched  = (int*)  ((char*)d_ws + 4849664);

    prep_kernel<<<929, 256, 0, stream>>>(Wa, relaW, linW, nbr_idx, nbr_deg,
                                         linP, relaP, sched);
    attn_kernel<<<N_DRUG, 256, 0, stream>>>(drugW, relaP, entW, drug_name,
                                            adj_tail, adj_rel, cat);
    gemm_h<<<dim3(72, 4), 512, 0, stream>>>(cat, linP, linb, out);
    scan_kernel<<<256, 64, 0, stream>>>(out, gamma, beta, nbr_idx, nbr_deg,
                                        epoch, sched);
}